// Round 3
// baseline (268.443 us; speedup 1.0000x reference)
//
#include <hip/hip_runtime.h>
#include <hip/hip_fp16.h>

#define NXK 2048
#define NYK 2048
#define NC  (NXK - 1)   // 2047 cells per dim

// ---------------- build v2: 4 cells/thread, float4 loads, 128 B contiguous store ----------------
// rec[cell] = 16 halfs: [f00,f01,f10,f11, gx00..gx11, gy00..gy11, gxy00..gxy11]
// gx = fx*dx, gy = fy*dy, gxy = fxy*dx*dy (premultiplied; raw fx ~ O(1e4) would
// lose fp16 accuracy, fx*dx ~ O(1) is safe).
__global__ __launch_bounds__(256) void build_kernel(
    const float* __restrict__ xk, const float* __restrict__ yk,
    const float* __restrict__ f,  const float* __restrict__ fx,
    const float* __restrict__ fy, const float* __restrict__ fxy,
    __half* __restrict__ rec)
{
    int j0 = (blockIdx.x * 256 + threadIdx.x) * 4;   // first of 4 cells
    int i  = blockIdx.y;
    if (j0 >= NC) return;

    float dx = xk[i + 1] - xk[i];
    bool tail = (j0 + 4 >= NYK);

    // 5-point stencils (points j0..j0+4) for both rows of all 4 arrays
    float fa[5], fb[5], xa[5], xb[5], ya[5], yb[5], za[5], zb[5], yv[5];
    size_t base = (size_t)i * NYK + j0;

    *(float4*)fa = *(const float4*)(f   + base);
    *(float4*)fb = *(const float4*)(f   + base + NYK);
    *(float4*)xa = *(const float4*)(fx  + base);
    *(float4*)xb = *(const float4*)(fx  + base + NYK);
    *(float4*)ya = *(const float4*)(fy  + base);
    *(float4*)yb = *(const float4*)(fy  + base + NYK);
    *(float4*)za = *(const float4*)(fxy + base);
    *(float4*)zb = *(const float4*)(fxy + base + NYK);
    *(float4*)yv = *(const float4*)(yk + j0);
    if (!tail) {
        fa[4] = f[base + 4];         fb[4] = f[base + NYK + 4];
        xa[4] = fx[base + 4];        xb[4] = fx[base + NYK + 4];
        ya[4] = fy[base + 4];        yb[4] = fy[base + NYK + 4];
        za[4] = fxy[base + 4];       zb[4] = fxy[base + NYK + 4];
        yv[4] = yk[j0 + 4];
    } else {
        fa[4] = fb[4] = xa[4] = xb[4] = ya[4] = yb[4] = za[4] = zb[4] = 0.0f;
        yv[4] = 0.0f;
    }

    union { __half h[16]; float4 v[2]; } r;
    __half* recp = rec + ((size_t)i * NC + j0) * 16;

    #pragma unroll
    for (int k = 0; k < 4; ++k) {
        int j = j0 + k;
        if (j >= NC) break;
        float dy  = yv[k + 1] - yv[k];
        float dxy = dx * dy;

        r.h[0]  = __float2half(fa[k]);
        r.h[1]  = __float2half(fa[k + 1]);
        r.h[2]  = __float2half(fb[k]);
        r.h[3]  = __float2half(fb[k + 1]);

        r.h[4]  = __float2half(xa[k] * dx);
        r.h[5]  = __float2half(xa[k + 1] * dx);
        r.h[6]  = __float2half(xb[k] * dx);
        r.h[7]  = __float2half(xb[k + 1] * dx);

        r.h[8]  = __float2half(ya[k] * dy);
        r.h[9]  = __float2half(ya[k + 1] * dy);
        r.h[10] = __float2half(yb[k] * dy);
        r.h[11] = __float2half(yb[k + 1] * dy);

        r.h[12] = __float2half(za[k] * dxy);
        r.h[13] = __float2half(za[k + 1] * dxy);
        r.h[14] = __float2half(zb[k] * dxy);
        r.h[15] = __float2half(zb[k + 1] * dxy);

        float4* outp = reinterpret_cast<float4*>(recp + (size_t)k * 16);
        outp[0] = r.v[0];
        outp[1] = r.v[1];
    }
}

// ---------------- gather v2: 2 queries/thread (split-half), MLP=2 lines ----------------
__device__ __forceinline__ void cell_and_weights(
    float xv, float yv,
    const float* __restrict__ xk, const float* __restrict__ yk,
    size_t& cell, float4& u, float4& v)
{
    int il = (int)floorf(xv * (float)(NXK - 1));
    il = min(max(il, 0), NXK - 2);
    while (il < NXK - 2 && xv >= xk[il + 1]) ++il;
    while (il > 0 && xv < xk[il]) --il;

    int jl = (int)floorf(yv * (float)(NYK - 1));
    jl = min(max(jl, 0), NYK - 2);
    while (jl < NYK - 2 && yv >= yk[jl + 1]) ++jl;
    while (jl > 0 && yv < yk[jl]) --jl;

    float x0 = xk[il], x1 = xk[il + 1];
    float dx = x1 - x0;
    float tx = (xv - x0) * ((dx == 0.0f) ? 0.0f : 1.0f / dx);
    float y0 = yk[jl], y1 = yk[jl + 1];
    float dy = y1 - y0;
    float ty = (yv - y0) * ((dy == 0.0f) ? 0.0f : 1.0f / dy);

    // t-powers through interpax's A_CUBIC (note A[3,3] = -1)
    u.x = 1.0f + tx * tx * (2.0f * tx - 3.0f);
    u.y = tx * tx * (3.0f - 2.0f * tx);
    u.z = tx * (1.0f + tx * (tx - 2.0f));
    u.w = -tx * tx * (1.0f + tx);

    v.x = 1.0f + ty * ty * (2.0f * ty - 3.0f);
    v.y = ty * ty * (3.0f - 2.0f * ty);
    v.z = ty * (1.0f + ty * (ty - 2.0f));
    v.w = -ty * ty * (1.0f + ty);

    cell = (size_t)il * NC + jl;
}

__device__ __forceinline__ float eval_record(float4 r0, float4 r1, float4 u, float4 v)
{
    union { float4 v[2]; __half2 h2[8]; } r;
    r.v[0] = r0; r.v[1] = r1;
    float2 a, b;
    a = __half22float2(r.h2[0]); b = __half22float2(r.h2[1]);
    float sf   = u.x * a.x + u.z * a.y + u.y * b.x + u.w * b.y;
    a = __half22float2(r.h2[2]); b = __half22float2(r.h2[3]);
    float sgx  = u.x * a.x + u.z * a.y + u.y * b.x + u.w * b.y;
    a = __half22float2(r.h2[4]); b = __half22float2(r.h2[5]);
    float sgy  = u.x * a.x + u.z * a.y + u.y * b.x + u.w * b.y;
    a = __half22float2(r.h2[6]); b = __half22float2(r.h2[7]);
    float sgxy = u.x * a.x + u.z * a.y + u.y * b.x + u.w * b.y;
    return v.x * sf + v.y * sgx + v.z * sgy + v.w * sgxy;
}

__global__ __launch_bounds__(256) void gather_kernel(
    const float* __restrict__ xq, const float* __restrict__ yq,
    const float* __restrict__ xk, const float* __restrict__ yk,
    const __half* __restrict__ rec,
    float* __restrict__ out, int nq)
{
    int t = blockIdx.x * blockDim.x + threadIdx.x;
    int half = (nq + 1) / 2;
    if (t >= half) return;
    int qa = t;
    int qb = t + half;
    bool hasB = (qb < nq);
    int qbs = hasB ? qb : qa;

    float xva = xq[qa], yva = yq[qa];
    float xvb = xq[qbs], yvb = yq[qbs];

    size_t ca, cb;
    float4 ua, va, ub, vb;
    cell_and_weights(xva, yva, xk, yk, ca, ua, va);
    cell_and_weights(xvb, yvb, xk, yk, cb, ub, vb);

    const float4* rpa = reinterpret_cast<const float4*>(rec) + ca * 2;
    const float4* rpb = reinterpret_cast<const float4*>(rec) + cb * 2;
    // issue all four loads before any use (2 independent lines in flight)
    float4 a0 = rpa[0];
    float4 a1 = rpa[1];
    float4 b0 = rpb[0];
    float4 b1 = rpb[1];

    out[qa] = eval_record(a0, a1, ua, va);
    if (hasB) out[qb] = eval_record(b0, b1, ub, vb);
}

// ---------------- fallback (direct gather, used only if ws too small) ----------------
__global__ __launch_bounds__(256) void interp2d_direct(
    const float* __restrict__ xq, const float* __restrict__ yq,
    const float* __restrict__ xk, const float* __restrict__ yk,
    const float* __restrict__ f,  const float* __restrict__ fx,
    const float* __restrict__ fy, const float* __restrict__ fxy,
    float* __restrict__ out, int nq)
{
    int q = blockIdx.x * blockDim.x + threadIdx.x;
    if (q >= nq) return;

    float xv = xq[q], yv = yq[q];
    size_t cell; float4 u, v;
    cell_and_weights(xv, yv, xk, yk, cell, u, v);
    int il = (int)(cell / NC), jl = (int)(cell % NC);
    float dx = xk[il + 1] - xk[il];
    float dy = yk[jl + 1] - yk[jl];

    long base = (long)il * NYK + jl;
    const float* p = f + base;
    float sf   = u.x * p[0] + u.z * p[1] + u.y * p[NYK] + u.w * p[NYK + 1];
    p = fx + base;
    float sfx  = u.x * p[0] + u.z * p[1] + u.y * p[NYK] + u.w * p[NYK + 1];
    p = fy + base;
    float sfy  = u.x * p[0] + u.z * p[1] + u.y * p[NYK] + u.w * p[NYK + 1];
    p = fxy + base;
    float sfxy = u.x * p[0] + u.z * p[1] + u.y * p[NYK] + u.w * p[NYK + 1];

    out[q] = v.x * sf + v.y * (sfx * dx) + v.z * (sfy * dy) + v.w * (sfxy * (dx * dy));
}

extern "C" void kernel_launch(void* const* d_in, const int* in_sizes, int n_in,
                              void* d_out, int out_size, void* d_ws, size_t ws_size,
                              hipStream_t stream) {
    const float* xq  = (const float*)d_in[0];
    const float* yq  = (const float*)d_in[1];
    const float* xk  = (const float*)d_in[2];
    const float* yk  = (const float*)d_in[3];
    const float* f   = (const float*)d_in[4];
    const float* fx  = (const float*)d_in[5];
    const float* fy  = (const float*)d_in[6];
    const float* fxy = (const float*)d_in[7];
    float* out = (float*)d_out;

    int nq = in_sizes[0];
    const size_t rec_bytes = (size_t)NC * NC * 16 * sizeof(__half);  // ~134 MB

    if (ws_size >= rec_bytes) {
        __half* rec = (__half*)d_ws;
        // 4 cells per thread along j
        dim3 bgrid((NC + 256 * 4 - 1) / (256 * 4), NC);
        build_kernel<<<bgrid, 256, 0, stream>>>(xk, yk, f, fx, fy, fxy, rec);
        int half = (nq + 1) / 2;
        int grid = (half + 255) / 256;
        gather_kernel<<<grid, 256, 0, stream>>>(xq, yq, xk, yk, rec, out, nq);
    } else {
        int grid = (nq + 255) / 256;
        interp2d_direct<<<grid, 256, 0, stream>>>(xq, yq, xk, yk, f, fx, fy, fxy, out, nq);
    }
}

// Round 4
// 263.872 us; speedup vs baseline: 1.0173x; 1.0173x over previous
//
#include <hip/hip_runtime.h>
#include <hip/hip_fp16.h>

#define NXK 2048
#define NYK 2048
#define NC  (NXK - 1)   // 2047 cells per dim

// ---------------- build (round-2 v1, proven): per-cell packed fp16 record (32 B) ----------------
// rec[cell] = 16 halfs: [f00,f01,f10,f11, gx00..gx11, gy00..gy11, gxy00..gxy11]
// gx = fx*dx, gy = fy*dy, gxy = fxy*dx*dy (premultiplied; raw fx ~ O(1e4) would
// lose fp16 accuracy, fx*dx ~ O(1) is safe).
__global__ __launch_bounds__(256) void build_kernel(
    const float* __restrict__ xk, const float* __restrict__ yk,
    const float* __restrict__ f,  const float* __restrict__ fx,
    const float* __restrict__ fy, const float* __restrict__ fxy,
    __half* __restrict__ rec)
{
    int j = blockIdx.x * blockDim.x + threadIdx.x;
    int i = blockIdx.y;
    if (j >= NC) return;

    size_t base = (size_t)i * NYK + j;
    float dx = xk[i + 1] - xk[i];
    float dy = yk[j + 1] - yk[j];
    float dxy = dx * dy;

    union { __half h[16]; float4 v[2]; } r;

    r.h[0]  = __float2half(f[base]);
    r.h[1]  = __float2half(f[base + 1]);
    r.h[2]  = __float2half(f[base + NYK]);
    r.h[3]  = __float2half(f[base + NYK + 1]);

    r.h[4]  = __float2half(fx[base] * dx);
    r.h[5]  = __float2half(fx[base + 1] * dx);
    r.h[6]  = __float2half(fx[base + NYK] * dx);
    r.h[7]  = __float2half(fx[base + NYK + 1] * dx);

    r.h[8]  = __float2half(fy[base] * dy);
    r.h[9]  = __float2half(fy[base + 1] * dy);
    r.h[10] = __float2half(fy[base + NYK] * dy);
    r.h[11] = __float2half(fy[base + NYK + 1] * dy);

    r.h[12] = __float2half(fxy[base] * dxy);
    r.h[13] = __float2half(fxy[base + 1] * dxy);
    r.h[14] = __float2half(fxy[base + NYK] * dxy);
    r.h[15] = __float2half(fxy[base + NYK + 1] * dxy);

    float4* outp = reinterpret_cast<float4*>(rec + ((size_t)i * NC + j) * 16);
    outp[0] = r.v[0];
    outp[1] = r.v[1];
}

// ---------------- gather v3: 4 queries/thread, 4 independent record lines in flight ----------------
__device__ __forceinline__ void cell_and_weights(
    float xv, float yv,
    const float* __restrict__ xk, const float* __restrict__ yk,
    size_t& cell, float4& u, float4& v)
{
    int il = (int)floorf(xv * (float)(NXK - 1));
    il = min(max(il, 0), NXK - 2);
    while (il < NXK - 2 && xv >= xk[il + 1]) ++il;
    while (il > 0 && xv < xk[il]) --il;

    int jl = (int)floorf(yv * (float)(NYK - 1));
    jl = min(max(jl, 0), NYK - 2);
    while (jl < NYK - 2 && yv >= yk[jl + 1]) ++jl;
    while (jl > 0 && yv < yk[jl]) --jl;

    float x0 = xk[il], x1 = xk[il + 1];
    float dx = x1 - x0;
    float tx = (xv - x0) * ((dx == 0.0f) ? 0.0f : 1.0f / dx);
    float y0 = yk[jl], y1 = yk[jl + 1];
    float dy = y1 - y0;
    float ty = (yv - y0) * ((dy == 0.0f) ? 0.0f : 1.0f / dy);

    // t-powers through interpax's A_CUBIC (note A[3,3] = -1)
    u.x = 1.0f + tx * tx * (2.0f * tx - 3.0f);
    u.y = tx * tx * (3.0f - 2.0f * tx);
    u.z = tx * (1.0f + tx * (tx - 2.0f));
    u.w = -tx * tx * (1.0f + tx);

    v.x = 1.0f + ty * ty * (2.0f * ty - 3.0f);
    v.y = ty * ty * (3.0f - 2.0f * ty);
    v.z = ty * (1.0f + ty * (ty - 2.0f));
    v.w = -ty * ty * (1.0f + ty);

    cell = (size_t)il * NC + jl;
}

__device__ __forceinline__ float eval_record(float4 r0, float4 r1, float4 u, float4 v)
{
    union { float4 v[2]; __half2 h2[8]; } r;
    r.v[0] = r0; r.v[1] = r1;
    float2 a, b;
    a = __half22float2(r.h2[0]); b = __half22float2(r.h2[1]);
    float sf   = u.x * a.x + u.z * a.y + u.y * b.x + u.w * b.y;
    a = __half22float2(r.h2[2]); b = __half22float2(r.h2[3]);
    float sgx  = u.x * a.x + u.z * a.y + u.y * b.x + u.w * b.y;
    a = __half22float2(r.h2[4]); b = __half22float2(r.h2[5]);
    float sgy  = u.x * a.x + u.z * a.y + u.y * b.x + u.w * b.y;
    a = __half22float2(r.h2[6]); b = __half22float2(r.h2[7]);
    float sgxy = u.x * a.x + u.z * a.y + u.y * b.x + u.w * b.y;
    return v.x * sf + v.y * sgx + v.z * sgy + v.w * sgxy;
}

__global__ __launch_bounds__(256) void gather_kernel(
    const float* __restrict__ xq, const float* __restrict__ yq,
    const float* __restrict__ xk, const float* __restrict__ yk,
    const __half* __restrict__ rec,
    float* __restrict__ out, int nq)
{
    int t = blockIdx.x * blockDim.x + threadIdx.x;
    int quarter = (nq + 3) / 4;
    if (t >= quarter) return;

    int qi[4];
    bool ok[4];
    float4 u[4], v[4];
    size_t cell[4];

    #pragma unroll
    for (int k = 0; k < 4; ++k) {
        int q = t + k * quarter;
        ok[k] = (q < nq);
        qi[k] = ok[k] ? q : t;
    }

    #pragma unroll
    for (int k = 0; k < 4; ++k) {
        float xv = xq[qi[k]];
        float yv = yq[qi[k]];
        cell_and_weights(xv, yv, xk, yk, cell[k], u[k], v[k]);
    }

    // issue all 8 record loads (4 independent 64 B lines) before any use
    float4 r0[4], r1[4];
    #pragma unroll
    for (int k = 0; k < 4; ++k) {
        const float4* rp = reinterpret_cast<const float4*>(rec) + cell[k] * 2;
        r0[k] = rp[0];
        r1[k] = rp[1];
    }

    #pragma unroll
    for (int k = 0; k < 4; ++k) {
        float res = eval_record(r0[k], r1[k], u[k], v[k]);
        if (ok[k]) out[qi[k]] = res;
    }
}

// ---------------- fallback (direct gather, used only if ws too small) ----------------
__global__ __launch_bounds__(256) void interp2d_direct(
    const float* __restrict__ xq, const float* __restrict__ yq,
    const float* __restrict__ xk, const float* __restrict__ yk,
    const float* __restrict__ f,  const float* __restrict__ fx,
    const float* __restrict__ fy, const float* __restrict__ fxy,
    float* __restrict__ out, int nq)
{
    int q = blockIdx.x * blockDim.x + threadIdx.x;
    if (q >= nq) return;

    float xv = xq[q], yv = yq[q];
    size_t cell; float4 u, v;
    cell_and_weights(xv, yv, xk, yk, cell, u, v);
    int il = (int)(cell / NC), jl = (int)(cell % NC);
    float dx = xk[il + 1] - xk[il];
    float dy = yk[jl + 1] - yk[jl];

    long base = (long)il * NYK + jl;
    const float* p = f + base;
    float sf   = u.x * p[0] + u.z * p[1] + u.y * p[NYK] + u.w * p[NYK + 1];
    p = fx + base;
    float sfx  = u.x * p[0] + u.z * p[1] + u.y * p[NYK] + u.w * p[NYK + 1];
    p = fy + base;
    float sfy  = u.x * p[0] + u.z * p[1] + u.y * p[NYK] + u.w * p[NYK + 1];
    p = fxy + base;
    float sfxy = u.x * p[0] + u.z * p[1] + u.y * p[NYK] + u.w * p[NYK + 1];

    out[q] = v.x * sf + v.y * (sfx * dx) + v.z * (sfy * dy) + v.w * (sfxy * (dx * dy));
}

extern "C" void kernel_launch(void* const* d_in, const int* in_sizes, int n_in,
                              void* d_out, int out_size, void* d_ws, size_t ws_size,
                              hipStream_t stream) {
    const float* xq  = (const float*)d_in[0];
    const float* yq  = (const float*)d_in[1];
    const float* xk  = (const float*)d_in[2];
    const float* yk  = (const float*)d_in[3];
    const float* f   = (const float*)d_in[4];
    const float* fx  = (const float*)d_in[5];
    const float* fy  = (const float*)d_in[6];
    const float* fxy = (const float*)d_in[7];
    float* out = (float*)d_out;

    int nq = in_sizes[0];
    const size_t rec_bytes = (size_t)NC * NC * 16 * sizeof(__half);  // ~134 MB

    if (ws_size >= rec_bytes) {
        __half* rec = (__half*)d_ws;
        dim3 bgrid((NC + 255) / 256, NC);
        build_kernel<<<bgrid, 256, 0, stream>>>(xk, yk, f, fx, fy, fxy, rec);
        int quarter = (nq + 3) / 4;
        int grid = (quarter + 255) / 256;
        gather_kernel<<<grid, 256, 0, stream>>>(xq, yq, xk, yk, rec, out, nq);
    } else {
        int grid = (nq + 255) / 256;
        interp2d_direct<<<grid, 256, 0, stream>>>(xq, yq, xk, yk, f, fx, fy, fxy, out, nq);
    }
}